// Round 1
// baseline (343.954 us; speedup 1.0000x reference)
//
#include <hip/hip_runtime.h>
#include <math.h>

#define DEV __device__ __forceinline__

// ============================ prep: weight transposes ============================
__global__ void prep_kernel(const float* __restrict__ w2,   // (16,64,3,3)
                            const float* __restrict__ fc1w, // (64,196)
                            const float* __restrict__ fc2w, // (128,64)
                            const float* __restrict__ fc3w, // (64,128)
                            const float* __restrict__ fc4w, // (10,64)
                            float* __restrict__ w2t,        // (9,64,16)
                            float* __restrict__ fc1t,       // (196,64)
                            float* __restrict__ fc2t,       // (64,128)
                            float* __restrict__ fc3t,       // (128,64)
                            float* __restrict__ fc4t)       // (64,10)
{
    int t = blockIdx.x * blockDim.x + threadIdx.x;
    int NT = gridDim.x * blockDim.x;
    for (int i = t; i < 9216; i += NT) {
        int oc = i / 576, r = i % 576, ic = r / 9, k = r % 9;
        w2t[(k * 64 + ic) * 16 + oc] = w2[i];
    }
    for (int i = t; i < 12544; i += NT) { int j = i / 196, k = i % 196; fc1t[k * 64 + j] = fc1w[i]; }
    for (int i = t; i < 8192;  i += NT) { int j = i / 64,  k = i % 64;  fc2t[k * 128 + j] = fc2w[i]; }
    for (int i = t; i < 8192;  i += NT) { int j = i / 128, k = i % 128; fc3t[k * 64 + j] = fc3w[i]; }
    for (int i = t; i < 640;   i += NT) { int j = i / 64,  k = i % 64;  fc4t[k * 10 + j] = fc4w[i]; }
}

// ============================ conv1 + relu + pool ============================
// x:(2048,1,28,28) w:(64,1,3,3) -> out1:(2048,64,14,14)
__global__ __launch_bounds__(256) void conv1_kernel(
    const float* __restrict__ x, const float* __restrict__ w1,
    const float* __restrict__ b1, float* __restrict__ out1)
{
    __shared__ float pin[30][32];     // zero-padded input, row stride 32
    __shared__ float wsh[64 * 9];
    __shared__ float bsh[64];
    int n = blockIdx.x, t = threadIdx.x;
    for (int i = t; i < 30 * 32; i += 256) ((float*)pin)[i] = 0.f;
    __syncthreads();
    for (int i = t; i < 784; i += 256) {
        int y = i / 28, xx = i % 28;
        pin[y + 1][xx + 1] = x[n * 784 + i];
    }
    for (int i = t; i < 576; i += 256) wsh[i] = w1[i];
    if (t < 64) bsh[t] = b1[t];
    __syncthreads();

    for (int k = 0; k < 49; ++k) {
        int o = t + 256 * k;               // exactly 12544 = 49*256 outputs
        int c = o / 196, pos = o % 196;
        int py = pos / 14, px = pos % 14;
        float v[4][4];
        #pragma unroll
        for (int dy = 0; dy < 4; ++dy)
            #pragma unroll
            for (int dx = 0; dx < 4; ++dx)
                v[dy][dx] = pin[2 * py + dy][2 * px + dx];
        const float* wc = &wsh[c * 9];
        float w0 = wc[0], w1v = wc[1], w2v = wc[2], w3v = wc[3], w4v = wc[4],
              w5v = wc[5], w6v = wc[6], w7v = wc[7], w8v = wc[8];
        float m = -INFINITY;
        #pragma unroll
        for (int dy = 0; dy < 2; ++dy)
            #pragma unroll
            for (int dx = 0; dx < 2; ++dx) {
                float s = w0 * v[dy][dx]     + w1v * v[dy][dx + 1]     + w2v * v[dy][dx + 2]
                        + w3v * v[dy + 1][dx] + w4v * v[dy + 1][dx + 1] + w5v * v[dy + 1][dx + 2]
                        + w6v * v[dy + 2][dx] + w7v * v[dy + 2][dx + 1] + w8v * v[dy + 2][dx + 2];
                m = fmaxf(m, s);
            }
        out1[n * 12544 + o] = fmaxf(m + bsh[c], 0.f);
    }
}

// ============================ conv2 + relu + pool ============================
// out1:(2048,64,14,14) w2t:(9,64,16) -> out2:(2048,16,7,7)
__global__ __launch_bounds__(256) void conv2_kernel(
    const float* __restrict__ out1, const float* __restrict__ w2t,
    const float* __restrict__ b2, float* __restrict__ out2)
{
    __shared__ float lds[64 * 196];    // 50176 B
    int n = blockIdx.x, t = threadIdx.x;
    for (int i = t; i < 12544; i += 256) lds[i] = out1[n * 12544 + i];
    __syncthreads();

    float acc[16];
    #pragma unroll
    for (int i = 0; i < 16; ++i) acc[i] = 0.f;
    int y = t / 14, x0 = t % 14;
    if (t < 196) {
        #pragma unroll
        for (int ky = 0; ky < 3; ++ky) {
            int yy = y + ky - 1;
            #pragma unroll
            for (int kx = 0; kx < 3; ++kx) {
                int xx = x0 + kx - 1;
                bool valid = ((unsigned)yy < 14u) && ((unsigned)xx < 14u);
                int base = valid ? yy * 14 + xx : 0;
                const float* wp = w2t + (ky * 3 + kx) * 64 * 16;
                for (int ic = 0; ic < 64; ++ic) {
                    float v = lds[ic * 196 + base];
                    v = valid ? v : 0.f;
                    const float* w = wp + ic * 16;   // uniform address -> scalar loads
                    #pragma unroll
                    for (int oc = 0; oc < 16; ++oc) acc[oc] = fmaf(w[oc], v, acc[oc]);
                }
            }
        }
    }
    __syncthreads();
    if (t < 196) {
        #pragma unroll
        for (int oc = 0; oc < 16; ++oc) lds[oc * 196 + t] = acc[oc];
    }
    __syncthreads();
    for (int o = t; o < 784; o += 256) {
        int c = o / 49, pp = o % 49, py = pp / 7, px = pp % 7;
        const float* base = lds + c * 196 + (2 * py) * 14 + 2 * px;
        float m = fmaxf(fmaxf(base[0], base[1]), fmaxf(base[14], base[15]));
        out2[n * 784 + o] = fmaxf(m + b2[c], 0.f);
    }
}

// ============================ quantum gates (compile-time unrolled) ============================
template<int B>
DEV void ry_b(float* sr, float* si, float c, float s) {
    #pragma unroll
    for (int i = 0; i < 16; ++i) if (!(i & B)) {
        int j = i | B;
        float r0 = sr[i], m0 = si[i], r1 = sr[j], m1 = si[j];
        sr[i] = c * r0 - s * r1;  si[i] = c * m0 - s * m1;
        sr[j] = s * r0 + c * r1;  si[j] = s * m0 + c * m1;
    }
}
template<int B>
DEV void rz_b(float* sr, float* si, float c, float s) {
    #pragma unroll
    for (int i = 0; i < 16; ++i) {
        float xr = sr[i], xi = si[i];
        if (!(i & B)) { sr[i] = c * xr + s * xi;  si[i] = c * xi - s * xr; }   // * e^{-ih}
        else          { sr[i] = c * xr - s * xi;  si[i] = c * xi + s * xr; }   // * e^{+ih}
    }
}
template<int BC, int BT>
DEV void cnot_b(float* sr, float* si) {
    #pragma unroll
    for (int i = 0; i < 16; ++i) if ((i & BC) && !(i & BT)) {
        int j = i | BT;
        float tr = sr[i]; sr[i] = sr[j]; sr[j] = tr;
        float ti = si[i]; si[i] = si[j]; si[j] = ti;
    }
}
template<int A, int Bw>
DEV void ansatz(float* sr, float* si, const float* cc, const float* ss) {
    constexpr int BA = 8 >> A, BB = 8 >> Bw;
    ry_b<BA>(sr, si, cc[0], ss[0]);
    rz_b<BA>(sr, si, cc[1], ss[1]);
    ry_b<BB>(sr, si, cc[2], ss[2]);
    rz_b<BB>(sr, si, cc[3], ss[3]);
    cnot_b<BA, BB>(sr, si);
    ry_b<BA>(sr, si, cc[4], ss[4]);
    rz_b<BA>(sr, si, cc[5], ss[5]);
    ry_b<BB>(sr, si, cc[6], ss[6]);
}

// ============================ conv3 + leaky + sigmoid + quantum circuit ============================
// out2:(2048,16,7,7) w3:(4,16,3,3) qp:(2,7) -> q:(2048,196)  feature = patch*4 + wire
__global__ __launch_bounds__(256) void qconv_kernel(
    const float* __restrict__ out2, const float* __restrict__ w3,
    const float* __restrict__ b3, const float* __restrict__ qp,
    float* __restrict__ q)
{
    int gid = blockIdx.x * 256 + threadIdx.x;   // 392*256 = 100352 exactly
    int n = gid / 49, pp = gid % 49;
    int py = pp / 7, px = pp % 7;
    const float* in = out2 + n * 784;

    float acc[4] = { b3[0], b3[1], b3[2], b3[3] };
    for (int ic = 0; ic < 16; ++ic) {
        #pragma unroll
        for (int ky = 0; ky < 3; ++ky) {
            int yy = py + ky - 1;
            int yc = min(max(yy, 0), 6);
            #pragma unroll
            for (int kx = 0; kx < 3; ++kx) {
                int xx = px + kx - 1;
                int xc = min(max(xx, 0), 6);
                bool valid = ((unsigned)yy < 7u) && ((unsigned)xx < 7u);
                float v = in[ic * 49 + yc * 7 + xc];
                v = valid ? v : 0.f;
                #pragma unroll
                for (int c = 0; c < 4; ++c)
                    acc[c] = fmaf(w3[(c * 16 + ic) * 9 + ky * 3 + kx], v, acc[c]);
            }
        }
    }
    // leaky relu -> sigmoid -> half-angle h = (pi/2)*sigmoid
    float h[4];
    #pragma unroll
    for (int c = 0; c < 4; ++c) {
        float z = acc[c];
        z = z > 0.f ? z : 0.01f * z;
        float sg = 1.f / (1.f + __expf(-z));
        h[c] = 1.5707963267948966f * sg;
    }

    // statevector in registers
    float sr[16], si[16];
    #pragma unroll
    for (int i = 0; i < 16; ++i) { sr[i] = 0.f; si[i] = 0.f; }
    sr[0] = 1.f;

    float ce, se;
    __sincosf(h[0], &se, &ce); ry_b<8>(sr, si, ce, se);
    __sincosf(h[1], &se, &ce); ry_b<4>(sr, si, ce, se);
    __sincosf(h[2], &se, &ce); ry_b<2>(sr, si, ce, se);
    __sincosf(h[3], &se, &ce); ry_b<1>(sr, si, ce, se);

    float cs0[7], sn0[7], cs1[7], sn1[7];
    #pragma unroll
    for (int k = 0; k < 7; ++k) {
        __sincosf(qp[k] * 0.5f, &sn0[k], &cs0[k]);
        __sincosf(qp[7 + k] * 0.5f, &sn1[k], &cs1[k]);
    }
    ansatz<0, 1>(sr, si, cs0, sn0);
    ansatz<1, 2>(sr, si, cs0, sn0);
    ansatz<2, 3>(sr, si, cs0, sn0);
    ansatz<3, 0>(sr, si, cs0, sn0);
    ansatz<0, 1>(sr, si, cs1, sn1);
    ansatz<1, 2>(sr, si, cs1, sn1);
    ansatz<2, 3>(sr, si, cs1, sn1);
    ansatz<3, 0>(sr, si, cs1, sn1);

    float p[16];
    #pragma unroll
    for (int i = 0; i < 16; ++i) p[i] = sr[i] * sr[i] + si[i] * si[i];

    float* qo = q + n * 196 + pp * 4;
    #pragma unroll
    for (int w = 0; w < 4; ++w) {
        int B = 8 >> w;
        float e = 0.f;
        #pragma unroll
        for (int i = 0; i < 16; ++i) e += (i & B) ? -p[i] : p[i];
        qo[w] = e;
    }
}

// ============================ fused MLP ============================
// q:(2048,196) -> out:(2048,10)
__global__ __launch_bounds__(64) void fc_kernel(
    const float* __restrict__ q,
    const float* __restrict__ fc1t, const float* __restrict__ fb1,
    const float* __restrict__ fc2t, const float* __restrict__ fb2,
    const float* __restrict__ fc3t, const float* __restrict__ fb3,
    const float* __restrict__ fc4t, const float* __restrict__ fb4,
    float* __restrict__ out)
{
    __shared__ float qr[196], h1[64], h2[128], h3[64];
    int n = blockIdx.x, t = threadIdx.x;
    for (int i = t; i < 196; i += 64) qr[i] = q[n * 196 + i];
    __syncthreads();
    float a = fb1[t];
    for (int k = 0; k < 196; ++k) a = fmaf(fc1t[k * 64 + t], qr[k], a);
    h1[t] = fmaxf(a, 0.f);
    __syncthreads();
    float a0 = fb2[t], a1 = fb2[t + 64];
    for (int k = 0; k < 64; ++k) {
        float v = h1[k];
        a0 = fmaf(fc2t[k * 128 + t], v, a0);
        a1 = fmaf(fc2t[k * 128 + t + 64], v, a1);
    }
    h2[t] = a0; h2[t + 64] = a1;
    __syncthreads();
    a = fb3[t];
    for (int k = 0; k < 128; ++k) a = fmaf(fc3t[k * 64 + t], h2[k], a);
    h3[t] = fmaxf(a, 0.f);
    __syncthreads();
    if (t < 10) {
        a = fb4[t];
        for (int k = 0; k < 64; ++k) a = fmaf(fc4t[k * 10 + t], h3[k], a);
        out[n * 10 + t] = a;
    }
}

// ============================ launch ============================
extern "C" void kernel_launch(void* const* d_in, const int* in_sizes, int n_in,
                              void* d_out, int out_size, void* d_ws, size_t ws_size,
                              hipStream_t stream) {
    const float* x      = (const float*)d_in[0];
    const float* c1w    = (const float*)d_in[1];
    const float* c1b    = (const float*)d_in[2];
    const float* c2w    = (const float*)d_in[3];
    const float* c2b    = (const float*)d_in[4];
    const float* c3w    = (const float*)d_in[5];
    const float* c3b    = (const float*)d_in[6];
    const float* qp     = (const float*)d_in[7];
    const float* fc1w   = (const float*)d_in[8];
    const float* fc1b   = (const float*)d_in[9];
    const float* fc2w   = (const float*)d_in[10];
    const float* fc2b   = (const float*)d_in[11];
    const float* fc3w   = (const float*)d_in[12];
    const float* fc3b   = (const float*)d_in[13];
    const float* fc4w   = (const float*)d_in[14];
    const float* fc4b   = (const float*)d_in[15];
    float* out = (float*)d_out;

    float* ws = (float*)d_ws;
    float* w2t  = ws;             // 9216
    float* fc1t = w2t + 9216;     // 12544
    float* fc2t = fc1t + 12544;   // 8192
    float* fc3t = fc2t + 8192;    // 8192
    float* fc4t = fc3t + 8192;    // 640
    float* out1 = fc4t + 640;               // 2048*12544
    float* out2 = out1 + 2048 * 12544;      // 2048*784
    float* qbuf = out2 + 2048 * 784;        // 2048*196

    prep_kernel<<<40, 256, 0, stream>>>(c2w, fc1w, fc2w, fc3w, fc4w,
                                        w2t, fc1t, fc2t, fc3t, fc4t);
    conv1_kernel<<<2048, 256, 0, stream>>>(x, c1w, c1b, out1);
    conv2_kernel<<<2048, 256, 0, stream>>>(out1, w2t, c2b, out2);
    qconv_kernel<<<392, 256, 0, stream>>>(out2, c3w, c3b, qp, qbuf);
    fc_kernel<<<2048, 64, 0, stream>>>(qbuf, fc1t, fc1b, fc2t, fc2b,
                                       fc3t, fc3b, fc4t, fc4b, out);
}

// Round 2
// 242.899 us; speedup vs baseline: 1.4160x; 1.4160x over previous
//
#include <hip/hip_runtime.h>
#include <hip/hip_bf16.h>
#include <math.h>

#define DEV __device__ __forceinline__

DEV float bf2f(unsigned short u) { return __uint_as_float(((unsigned)u) << 16); }

// ============================ prep: weight transposes ============================
// w2t layout: [(q*9 + tap)*16 + ic_l][oc]  (quarter-major so each stage copy is contiguous)
__global__ void prep_kernel(const float* __restrict__ w2,   // (16,64,3,3)
                            const float* __restrict__ fc1w, // (64,196)
                            const float* __restrict__ fc2w, // (128,64)
                            const float* __restrict__ fc3w, // (64,128)
                            const float* __restrict__ fc4w, // (10,64)
                            float* __restrict__ w2t,        // (4,9,16,16)
                            float* __restrict__ fc1t,       // (196,64)
                            float* __restrict__ fc2t,       // (64,128)
                            float* __restrict__ fc3t,       // (128,64)
                            float* __restrict__ fc4t)       // (64,10)
{
    int t = blockIdx.x * blockDim.x + threadIdx.x;
    int NT = gridDim.x * blockDim.x;
    for (int i = t; i < 9216; i += NT) {
        int oc = i & 15, icl = (i >> 4) & 15, tap = (i >> 8) % 9, q = i / 2304;
        w2t[i] = w2[(oc * 64 + q * 16 + icl) * 9 + tap];
    }
    for (int i = t; i < 12544; i += NT) { int j = i / 196, k = i % 196; fc1t[k * 64 + j] = fc1w[i]; }
    for (int i = t; i < 8192;  i += NT) { int j = i / 64,  k = i % 64;  fc2t[k * 128 + j] = fc2w[i]; }
    for (int i = t; i < 8192;  i += NT) { int j = i / 128, k = i % 128; fc3t[k * 64 + j] = fc3w[i]; }
    for (int i = t; i < 640;   i += NT) { int j = i / 64,  k = i % 64;  fc4t[k * 10 + j] = fc4w[i]; }
}

// ============================ conv1 + relu + pool (bf16 out) ============================
// x:(2048,1,28,28) w:(64,1,3,3) -> out1:(2048,64,14,14) bf16
__global__ __launch_bounds__(256) void conv1_kernel(
    const float* __restrict__ x, const float* __restrict__ w1,
    const float* __restrict__ b1, __hip_bfloat16* __restrict__ out1)
{
    __shared__ float pin[30][32];     // zero-padded input, row stride 32
    __shared__ float wsh[64 * 9];
    __shared__ float bsh[64];
    int n = blockIdx.x, t = threadIdx.x;
    for (int i = t; i < 30 * 32; i += 256) ((float*)pin)[i] = 0.f;
    __syncthreads();
    for (int i = t; i < 784; i += 256) {
        int y = i / 28, xx = i % 28;
        pin[y + 1][xx + 1] = x[n * 784 + i];
    }
    for (int i = t; i < 576; i += 256) wsh[i] = w1[i];
    if (t < 64) bsh[t] = b1[t];
    __syncthreads();

    for (int k = 0; k < 49; ++k) {
        int o = t + 256 * k;               // exactly 12544 = 49*256 outputs
        int c = o / 196, pos = o % 196;
        int py = pos / 14, px = pos % 14;
        float v[4][4];
        #pragma unroll
        for (int dy = 0; dy < 4; ++dy)
            #pragma unroll
            for (int dx = 0; dx < 4; ++dx)
                v[dy][dx] = pin[2 * py + dy][2 * px + dx];
        const float* wc = &wsh[c * 9];
        float w0 = wc[0], w1v = wc[1], w2v = wc[2], w3v = wc[3], w4v = wc[4],
              w5v = wc[5], w6v = wc[6], w7v = wc[7], w8v = wc[8];
        float m = -INFINITY;
        #pragma unroll
        for (int dy = 0; dy < 2; ++dy)
            #pragma unroll
            for (int dx = 0; dx < 2; ++dx) {
                float s = w0 * v[dy][dx]     + w1v * v[dy][dx + 1]     + w2v * v[dy][dx + 2]
                        + w3v * v[dy + 1][dx] + w4v * v[dy + 1][dx + 1] + w5v * v[dy + 1][dx + 2]
                        + w6v * v[dy + 2][dx] + w7v * v[dy + 2][dx + 1] + w8v * v[dy + 2][dx + 2];
                m = fmaxf(m, s);
            }
        out1[n * 12544 + o] = __float2bfloat16(fmaxf(m + bsh[c], 0.f));
    }
}

// ============================ conv2 + relu + pool ============================
// out1:(2048,64,14,14) bf16, w2t:(4,9,16,16) -> out2:(2048,16,7,7) f32
// Block: 4 images (one per wave). Thread (lane<49) = pooled position, computes
// 2x2 pre-pool window x 16 oc = 64 accumulators. ic staged in 4 quarters.
__global__ __launch_bounds__(256, 3) void conv2_kernel(
    const __hip_bfloat16* __restrict__ out1, const float* __restrict__ w2t,
    const float* __restrict__ b2, float* __restrict__ out2)
{
    __shared__ unsigned short in_l[4 * 16 * 16 * 16];  // [img][ic][row 16][col 16] bf16, zero-padded
    __shared__ float w_l[2304];                        // [tap 9][ic 16][oc 16]
    int t = threadIdx.x;
    int wave = t >> 6, lane = t & 63;
    int n0 = blockIdx.x * 4;

    // zero once; staging only writes interior so pads stay zero
    for (int i = t; i < 8192; i += 256) ((unsigned*)in_l)[i] = 0u;

    float acc[2][2][16];
    #pragma unroll
    for (int a = 0; a < 2; ++a)
        #pragma unroll
        for (int b = 0; b < 2; ++b)
            #pragma unroll
            for (int o = 0; o < 16; ++o) acc[a][b][o] = 0.f;

    int py = lane / 7, px = lane % 7;
    bool active = lane < 49;

    for (int q = 0; q < 4; ++q) {
        __syncthreads();
        for (int i = t; i < 2304; i += 256) w_l[i] = w2t[q * 2304 + i];
        // stage 4 images x 16 ic x 196 bf16, as ushort2 (pairs never cross a row)
        for (int i = t; i < 6272; i += 256) {
            int m = i / 1568, j = i - m * 1568;
            ushort2 v = reinterpret_cast<const ushort2*>(
                out1 + (size_t)(n0 + m) * 12544 + q * 3136)[j];
            int p = j * 2;
            int ic = p / 196, pos = p - ic * 196;
            int yy = pos / 14, xx = pos - yy * 14;
            unsigned short* dst = in_l + ((m * 16 + ic) * 16 + (yy + 1)) * 16 + (xx + 1);
            dst[0] = v.x;
            dst[1] = v.y;
        }
        __syncthreads();
        if (active) {
            const unsigned short* my_in = in_l + wave * 16 * 256;
            for (int ic = 0; ic < 16; ++ic) {
                const unsigned short* ib = my_in + (ic * 16 + 2 * py) * 16 + 2 * px;
                float patch[4][4];
                #pragma unroll
                for (int r = 0; r < 4; ++r) {
                    unsigned p01 = *reinterpret_cast<const unsigned*>(ib + r * 16);
                    unsigned p23 = *reinterpret_cast<const unsigned*>(ib + r * 16 + 2);
                    patch[r][0] = __uint_as_float(p01 << 16);
                    patch[r][1] = __uint_as_float(p01 & 0xffff0000u);
                    patch[r][2] = __uint_as_float(p23 << 16);
                    patch[r][3] = __uint_as_float(p23 & 0xffff0000u);
                }
                const float* wb = w_l + ic * 16;
                #pragma unroll
                for (int ky = 0; ky < 3; ++ky)
                    #pragma unroll
                    for (int kx = 0; kx < 3; ++kx) {
                        const float* wp = wb + (ky * 3 + kx) * 256;
                        #pragma unroll
                        for (int o = 0; o < 16; ++o) {
                            float w = wp[o];
                            #pragma unroll
                            for (int dy = 0; dy < 2; ++dy)
                                #pragma unroll
                                for (int dx = 0; dx < 2; ++dx)
                                    acc[dy][dx][o] = fmaf(w, patch[ky + dy][kx + dx], acc[dy][dx][o]);
                        }
                    }
            }
        }
    }
    if (active) {
        float* outp = out2 + (size_t)(n0 + wave) * 784;
        #pragma unroll
        for (int o = 0; o < 16; ++o) {
            float m = fmaxf(fmaxf(acc[0][0][o], acc[0][1][o]),
                            fmaxf(acc[1][0][o], acc[1][1][o]));
            outp[o * 49 + py * 7 + px] = fmaxf(m + b2[o], 0.f);
        }
    }
}

// ============================ quantum gates (compile-time unrolled) ============================
template<int B>
DEV void ry_b(float* sr, float* si, float c, float s) {
    #pragma unroll
    for (int i = 0; i < 16; ++i) if (!(i & B)) {
        int j = i | B;
        float r0 = sr[i], m0 = si[i], r1 = sr[j], m1 = si[j];
        sr[i] = c * r0 - s * r1;  si[i] = c * m0 - s * m1;
        sr[j] = s * r0 + c * r1;  si[j] = s * m0 + c * m1;
    }
}
template<int B>
DEV void rz_b(float* sr, float* si, float c, float s) {
    #pragma unroll
    for (int i = 0; i < 16; ++i) {
        float xr = sr[i], xi = si[i];
        if (!(i & B)) { sr[i] = c * xr + s * xi;  si[i] = c * xi - s * xr; }
        else          { sr[i] = c * xr - s * xi;  si[i] = c * xi + s * xr; }
    }
}
template<int BC, int BT>
DEV void cnot_b(float* sr, float* si) {
    #pragma unroll
    for (int i = 0; i < 16; ++i) if ((i & BC) && !(i & BT)) {
        int j = i | BT;
        float tr = sr[i]; sr[i] = sr[j]; sr[j] = tr;
        float ti = si[i]; si[i] = si[j]; si[j] = ti;
    }
}
template<int A, int Bw>
DEV void ansatz(float* sr, float* si, const float* cc, const float* ss) {
    constexpr int BA = 8 >> A, BB = 8 >> Bw;
    ry_b<BA>(sr, si, cc[0], ss[0]);
    rz_b<BA>(sr, si, cc[1], ss[1]);
    ry_b<BB>(sr, si, cc[2], ss[2]);
    rz_b<BB>(sr, si, cc[3], ss[3]);
    cnot_b<BA, BB>(sr, si);
    ry_b<BA>(sr, si, cc[4], ss[4]);
    rz_b<BA>(sr, si, cc[5], ss[5]);
    ry_b<BB>(sr, si, cc[6], ss[6]);
}

// ============================ conv3 + leaky + sigmoid + quantum circuit ============================
__global__ __launch_bounds__(256) void qconv_kernel(
    const float* __restrict__ out2, const float* __restrict__ w3,
    const float* __restrict__ b3, const float* __restrict__ qp,
    float* __restrict__ q)
{
    int gid = blockIdx.x * 256 + threadIdx.x;   // 392*256 = 100352 exactly
    int n = gid / 49, pp = gid % 49;
    int py = pp / 7, px = pp % 7;
    const float* in = out2 + n * 784;

    float acc[4] = { b3[0], b3[1], b3[2], b3[3] };
    for (int ic = 0; ic < 16; ++ic) {
        #pragma unroll
        for (int ky = 0; ky < 3; ++ky) {
            int yy = py + ky - 1;
            int yc = min(max(yy, 0), 6);
            #pragma unroll
            for (int kx = 0; kx < 3; ++kx) {
                int xx = px + kx - 1;
                int xc = min(max(xx, 0), 6);
                bool valid = ((unsigned)yy < 7u) && ((unsigned)xx < 7u);
                float v = in[ic * 49 + yc * 7 + xc];
                v = valid ? v : 0.f;
                #pragma unroll
                for (int c = 0; c < 4; ++c)
                    acc[c] = fmaf(w3[(c * 16 + ic) * 9 + ky * 3 + kx], v, acc[c]);
            }
        }
    }
    float h[4];
    #pragma unroll
    for (int c = 0; c < 4; ++c) {
        float z = acc[c];
        z = z > 0.f ? z : 0.01f * z;
        float sg = 1.f / (1.f + __expf(-z));
        h[c] = 1.5707963267948966f * sg;
    }

    float sr[16], si[16];
    #pragma unroll
    for (int i = 0; i < 16; ++i) { sr[i] = 0.f; si[i] = 0.f; }
    sr[0] = 1.f;

    float ce, se;
    __sincosf(h[0], &se, &ce); ry_b<8>(sr, si, ce, se);
    __sincosf(h[1], &se, &ce); ry_b<4>(sr, si, ce, se);
    __sincosf(h[2], &se, &ce); ry_b<2>(sr, si, ce, se);
    __sincosf(h[3], &se, &ce); ry_b<1>(sr, si, ce, se);

    float cs0[7], sn0[7], cs1[7], sn1[7];
    #pragma unroll
    for (int k = 0; k < 7; ++k) {
        __sincosf(qp[k] * 0.5f, &sn0[k], &cs0[k]);
        __sincosf(qp[7 + k] * 0.5f, &sn1[k], &cs1[k]);
    }
    ansatz<0, 1>(sr, si, cs0, sn0);
    ansatz<1, 2>(sr, si, cs0, sn0);
    ansatz<2, 3>(sr, si, cs0, sn0);
    ansatz<3, 0>(sr, si, cs0, sn0);
    ansatz<0, 1>(sr, si, cs1, sn1);
    ansatz<1, 2>(sr, si, cs1, sn1);
    ansatz<2, 3>(sr, si, cs1, sn1);
    ansatz<3, 0>(sr, si, cs1, sn1);

    float p[16];
    #pragma unroll
    for (int i = 0; i < 16; ++i) p[i] = sr[i] * sr[i] + si[i] * si[i];

    float* qo = q + n * 196 + pp * 4;
    #pragma unroll
    for (int w = 0; w < 4; ++w) {
        int B = 8 >> w;
        float e = 0.f;
        #pragma unroll
        for (int i = 0; i < 16; ++i) e += (i & B) ? -p[i] : p[i];
        qo[w] = e;
    }
}

// ============================ fused MLP ============================
__global__ __launch_bounds__(64) void fc_kernel(
    const float* __restrict__ q,
    const float* __restrict__ fc1t, const float* __restrict__ fb1,
    const float* __restrict__ fc2t, const float* __restrict__ fb2,
    const float* __restrict__ fc3t, const float* __restrict__ fb3,
    const float* __restrict__ fc4t, const float* __restrict__ fb4,
    float* __restrict__ out)
{
    __shared__ float qr[196], h1[64], h2[128], h3[64];
    int n = blockIdx.x, t = threadIdx.x;
    for (int i = t; i < 196; i += 64) qr[i] = q[n * 196 + i];
    __syncthreads();
    float a = fb1[t];
    for (int k = 0; k < 196; ++k) a = fmaf(fc1t[k * 64 + t], qr[k], a);
    h1[t] = fmaxf(a, 0.f);
    __syncthreads();
    float a0 = fb2[t], a1 = fb2[t + 64];
    for (int k = 0; k < 64; ++k) {
        float v = h1[k];
        a0 = fmaf(fc2t[k * 128 + t], v, a0);
        a1 = fmaf(fc2t[k * 128 + t + 64], v, a1);
    }
    h2[t] = a0; h2[t + 64] = a1;
    __syncthreads();
    a = fb3[t];
    for (int k = 0; k < 128; ++k) a = fmaf(fc3t[k * 64 + t], h2[k], a);
    h3[t] = fmaxf(a, 0.f);
    __syncthreads();
    if (t < 10) {
        a = fb4[t];
        for (int k = 0; k < 64; ++k) a = fmaf(fc4t[k * 10 + t], h3[k], a);
        out[n * 10 + t] = a;
    }
}

// ============================ launch ============================
extern "C" void kernel_launch(void* const* d_in, const int* in_sizes, int n_in,
                              void* d_out, int out_size, void* d_ws, size_t ws_size,
                              hipStream_t stream) {
    const float* x      = (const float*)d_in[0];
    const float* c1w    = (const float*)d_in[1];
    const float* c1b    = (const float*)d_in[2];
    const float* c2w    = (const float*)d_in[3];
    const float* c2b    = (const float*)d_in[4];
    const float* c3w    = (const float*)d_in[5];
    const float* c3b    = (const float*)d_in[6];
    const float* qp     = (const float*)d_in[7];
    const float* fc1w   = (const float*)d_in[8];
    const float* fc1b   = (const float*)d_in[9];
    const float* fc2w   = (const float*)d_in[10];
    const float* fc2b   = (const float*)d_in[11];
    const float* fc3w   = (const float*)d_in[12];
    const float* fc3b   = (const float*)d_in[13];
    const float* fc4w   = (const float*)d_in[14];
    const float* fc4b   = (const float*)d_in[15];
    float* out = (float*)d_out;

    float* ws = (float*)d_ws;
    float* w2t  = ws;                       // 9216
    float* fc1t = w2t + 9216;               // 12544
    float* fc2t = fc1t + 12544;             // 8192
    float* fc3t = fc2t + 8192;              // 8192
    float* fc4t = fc3t + 8192;              // 640
    __hip_bfloat16* out1 = (__hip_bfloat16*)(fc4t + 640);   // 2048*12544 bf16
    float* out2 = (float*)(out1 + (size_t)2048 * 12544);    // 2048*784 f32
    float* qbuf = out2 + (size_t)2048 * 784;                // 2048*196 f32

    prep_kernel<<<40, 256, 0, stream>>>(c2w, fc1w, fc2w, fc3w, fc4w,
                                        w2t, fc1t, fc2t, fc3t, fc4t);
    conv1_kernel<<<2048, 256, 0, stream>>>(x, c1w, c1b, out1);
    conv2_kernel<<<512, 256, 0, stream>>>(out1, w2t, c2b, out2);
    qconv_kernel<<<392, 256, 0, stream>>>(out2, c3w, c3b, qp, qbuf);
    fc_kernel<<<2048, 64, 0, stream>>>(qbuf, fc1t, fc1b, fc2t, fc2b,
                                       fc3t, fc3b, fc4t, fc4b, out);
}

// Round 3
// 99.295 us; speedup vs baseline: 3.4640x; 2.4462x over previous
//
#include <hip/hip_runtime.h>
#include <hip/hip_bf16.h>
#include <math.h>

#define DEV __device__ __forceinline__

typedef __attribute__((ext_vector_type(4))) float f32x4;
typedef __attribute__((ext_vector_type(8))) short bf16x8;

DEV unsigned short f2bf(float v) {
    __hip_bfloat16 h = __float2bfloat16(v);
    return *reinterpret_cast<unsigned short*>(&h);
}

// ============================ prep: weight transposes ============================
// w2b: bf16, index i = ((tap*2+kk)*4 + fq)*128 + oc*8 + j  -> W2[oc][kk*32+fq*8+j][tap]
__global__ void prep_kernel(const float* __restrict__ w2,   // (16,64,3,3)
                            const float* __restrict__ fc1w, // (64,196)
                            const float* __restrict__ fc2w, // (128,64)
                            const float* __restrict__ fc3w, // (64,128)
                            const float* __restrict__ fc4w, // (10,64)
                            unsigned short* __restrict__ w2b, // 9216 bf16
                            float* __restrict__ fc1t,        // (196,64)
                            float* __restrict__ fc2t,        // (64,128)
                            float* __restrict__ fc3t,        // (128,64)
                            float* __restrict__ fc4t)        // (64,10)
{
    int t = blockIdx.x * blockDim.x + threadIdx.x;
    int NT = gridDim.x * blockDim.x;
    for (int i = t; i < 9216; i += NT) {
        int j = i & 7, oc = (i >> 3) & 15, fq = (i >> 7) & 3, f = i >> 9;
        int tap = f >> 1, kk = f & 1;
        int ic = kk * 32 + fq * 8 + j;
        w2b[i] = f2bf(w2[(oc * 64 + ic) * 9 + tap]);
    }
    for (int i = t; i < 12544; i += NT) { int j = i / 196, k = i % 196; fc1t[k * 64 + j] = fc1w[i]; }
    for (int i = t; i < 8192;  i += NT) { int j = i / 64,  k = i % 64;  fc2t[k * 128 + j] = fc2w[i]; }
    for (int i = t; i < 8192;  i += NT) { int j = i / 128, k = i % 128; fc3t[k * 64 + j] = fc3w[i]; }
    for (int i = t; i < 640;   i += NT) { int j = i / 64,  k = i % 64;  fc4t[k * 10 + j] = fc4w[i]; }
}

// ============================ conv1 + relu + pool (NHWC bf16 out) ============================
// x:(2048,1,28,28) -> out1:(2048, 196 pos, 64 ch) bf16.  lane = channel, pos wave-uniform.
__global__ __launch_bounds__(256, 8) void conv1_kernel(
    const float* __restrict__ x, const float* __restrict__ w1,
    const float* __restrict__ b1, unsigned short* __restrict__ out1)
{
    __shared__ float pin[30][32];     // zero-padded input
    __shared__ float wsh[576];
    __shared__ float bsh[64];
    int n = blockIdx.x, t = threadIdx.x, lane = t & 63;
    for (int i = t; i < 960; i += 256) ((float*)pin)[i] = 0.f;
    __syncthreads();
    for (int i = t; i < 784; i += 256) pin[i / 28 + 1][i % 28 + 1] = x[n * 784 + i];
    for (int i = t; i < 576; i += 256) wsh[i] = w1[i];
    if (t < 64) bsh[t] = b1[t];
    __syncthreads();

    float wr[9];
    #pragma unroll
    for (int i = 0; i < 9; ++i) wr[i] = wsh[lane * 9 + i];   // 2-way bank alias: free
    float bias = bsh[lane];
    unsigned short* op = out1 + (size_t)n * 12544;

    for (int k = 0; k < 49; ++k) {
        int pos = (t >> 6) + 4 * k;          // wave-uniform -> broadcast LDS reads
        int y = pos / 14, xx = pos - y * 14;
        float p[4][4];
        #pragma unroll
        for (int dy = 0; dy < 4; ++dy)
            #pragma unroll
            for (int dx = 0; dx < 4; ++dx)
                p[dy][dx] = pin[2 * y + dy][2 * xx + dx];
        float m = -INFINITY;
        #pragma unroll
        for (int dy = 0; dy < 2; ++dy)
            #pragma unroll
            for (int dx = 0; dx < 2; ++dx) {
                float s = wr[0]*p[dy][dx]   + wr[1]*p[dy][dx+1]   + wr[2]*p[dy][dx+2]
                        + wr[3]*p[dy+1][dx] + wr[4]*p[dy+1][dx+1] + wr[5]*p[dy+1][dx+2]
                        + wr[6]*p[dy+2][dx] + wr[7]*p[dy+2][dx+1] + wr[8]*p[dy+2][dx+2];
                m = fmaxf(m, s);
            }
        op[pos * 64 + lane] = f2bf(fmaxf(m + bias, 0.f));
    }
}

// ============================ conv2 via MFMA (9 shifted GEMMs) + pool ============================
// out1 NHWC bf16 -> out2:(2048,16,7,7) f32.  1 image/block, 13 M-tiles over 4 waves.
__global__ __launch_bounds__(256, 4) void conv2_kernel(
    const unsigned short* __restrict__ out1, const unsigned short* __restrict__ w2b,
    const float* __restrict__ b2, float* __restrict__ out2)
{
    __shared__ unsigned short in_l[16384];   // 32 KB padded 16x16 grid x 64 ic, XOR-swizzled
    float* d_l = (float*)in_l;               // aliased pre-pool buffer [196][17] f32
    int t = threadIdx.x, lane = t & 63, fq = lane >> 4, fr = lane & 15, wv = t >> 6;
    int n = blockIdx.x;

    // B fragments straight from L2 (identical across blocks)
    bf16x8 bfrag[18];
    const bf16x8* wb = (const bf16x8*)w2b;
    #pragma unroll
    for (int f = 0; f < 18; ++f) bfrag[f] = wb[(f * 4 + fq) * 16 + fr];

    for (int i = t; i < 2048; i += 256) ((f32x4*)in_l)[i] = f32x4{0.f, 0.f, 0.f, 0.f};
    __syncthreads();

    const ushort2* src = (const ushort2*)(out1 + (size_t)n * 12544);
    for (int i = t; i < 6272; i += 256) {
        int pos = i >> 5, icp = i & 31;
        int y = pos / 14, xx = pos - y * 14;
        int grid = (y + 1) * 16 + (xx + 1);
        int byte = (grid * 128 + icp * 4) ^ ((grid & 7) << 4);
        *(ushort2*)((char*)in_l + byte) = src[i];
    }
    __syncthreads();

    for (int r = 0; r < 4; ++r) {
        int tile = r * 4 + wv;
        bool tv = tile < 13;
        f32x4 acc = {0.f, 0.f, 0.f, 0.f};
        int pd0 = tile * 16 + fq * 4;
        if (tv) {
            int pos = tile * 16 + fr; pos = pos > 195 ? 195 : pos;   // clamp tail tile
            int y = pos / 14, xx = pos - y * 14;
            int g0 = y * 16 + xx;
            int vb = g0 * 128 + fq * 16;
            #pragma unroll
            for (int ky = 0; ky < 3; ++ky)
                #pragma unroll
                for (int kx = 0; kx < 3; ++kx) {
                    int dg = ky * 16 + kx;
                    int msk = ((g0 + dg) & 7) << 4;
                    int lin = vb + dg * 128;
                    bf16x8 a0 = *(const bf16x8*)((const char*)in_l + (lin ^ msk));
                    acc = __builtin_amdgcn_mfma_f32_16x16x32_bf16(a0, bfrag[(ky * 3 + kx) * 2], acc, 0, 0, 0);
                    bf16x8 a1 = *(const bf16x8*)((const char*)in_l + ((lin | 64) ^ msk));
                    acc = __builtin_amdgcn_mfma_f32_16x16x32_bf16(a1, bfrag[(ky * 3 + kx) * 2 + 1], acc, 0, 0, 0);
                }
        }
        __syncthreads();                      // all reads of this round done
        if (tv) {
            #pragma unroll
            for (int reg = 0; reg < 4; ++reg) {
                int pd = pd0 + reg;
                if (pd < 196) d_l[pd * 17 + fr] = acc[reg];
            }
        }
        __syncthreads();                      // writes visible; ranges for next round disjoint
    }

    float* op = out2 + (size_t)n * 784;
    for (int i = t; i < 784; i += 256) {
        int oc = i & 15, p7 = i >> 4;
        int y7 = p7 / 7, x7 = p7 % 7;
        int p00 = (2 * y7) * 14 + 2 * x7;
        float m = fmaxf(fmaxf(d_l[p00 * 17 + oc], d_l[(p00 + 1) * 17 + oc]),
                        fmaxf(d_l[(p00 + 14) * 17 + oc], d_l[(p00 + 15) * 17 + oc]));
        op[oc * 49 + p7] = fmaxf(m + b2[oc], 0.f);
    }
}

// ============================ quantum gates (compile-time unrolled) ============================
template<int B>
DEV void ry_b(float* sr, float* si, float c, float s) {
    #pragma unroll
    for (int i = 0; i < 16; ++i) if (!(i & B)) {
        int j = i | B;
        float r0 = sr[i], m0 = si[i], r1 = sr[j], m1 = si[j];
        sr[i] = c * r0 - s * r1;  si[i] = c * m0 - s * m1;
        sr[j] = s * r0 + c * r1;  si[j] = s * m0 + c * m1;
    }
}
template<int B>
DEV void rz_b(float* sr, float* si, float c, float s) {
    #pragma unroll
    for (int i = 0; i < 16; ++i) {
        float xr = sr[i], xi = si[i];
        if (!(i & B)) { sr[i] = c * xr + s * xi;  si[i] = c * xi - s * xr; }
        else          { sr[i] = c * xr - s * xi;  si[i] = c * xi + s * xr; }
    }
}
template<int BC, int BT>
DEV void cnot_b(float* sr, float* si) {
    #pragma unroll
    for (int i = 0; i < 16; ++i) if ((i & BC) && !(i & BT)) {
        int j = i | BT;
        float tr = sr[i]; sr[i] = sr[j]; sr[j] = tr;
        float ti = si[i]; si[i] = si[j]; si[j] = ti;
    }
}
template<int A, int Bw>
DEV void ansatz(float* sr, float* si, const float* cc, const float* ss) {
    constexpr int BA = 8 >> A, BB = 8 >> Bw;
    ry_b<BA>(sr, si, cc[0], ss[0]);
    rz_b<BA>(sr, si, cc[1], ss[1]);
    ry_b<BB>(sr, si, cc[2], ss[2]);
    rz_b<BB>(sr, si, cc[3], ss[3]);
    cnot_b<BA, BB>(sr, si);
    ry_b<BA>(sr, si, cc[4], ss[4]);
    rz_b<BA>(sr, si, cc[5], ss[5]);
    ry_b<BB>(sr, si, cc[6], ss[6]);
}

// ============================ conv3 + leaky + sigmoid + quantum circuit ============================
__global__ __launch_bounds__(256) void qconv_kernel(
    const float* __restrict__ out2, const float* __restrict__ w3,
    const float* __restrict__ b3, const float* __restrict__ qp,
    float* __restrict__ q)
{
    int gid = blockIdx.x * 256 + threadIdx.x;   // 392*256 = 100352 exactly
    int n = gid / 49, pp = gid % 49;
    int py = pp / 7, px = pp % 7;
    const float* in = out2 + n * 784;

    float acc[4] = { b3[0], b3[1], b3[2], b3[3] };
    for (int ic = 0; ic < 16; ++ic) {
        #pragma unroll
        for (int ky = 0; ky < 3; ++ky) {
            int yy = py + ky - 1;
            int yc = min(max(yy, 0), 6);
            #pragma unroll
            for (int kx = 0; kx < 3; ++kx) {
                int xx = px + kx - 1;
                int xc = min(max(xx, 0), 6);
                bool valid = ((unsigned)yy < 7u) && ((unsigned)xx < 7u);
                float v = in[ic * 49 + yc * 7 + xc];
                v = valid ? v : 0.f;
                #pragma unroll
                for (int c = 0; c < 4; ++c)
                    acc[c] = fmaf(w3[(c * 16 + ic) * 9 + ky * 3 + kx], v, acc[c]);
            }
        }
    }
    float h[4];
    #pragma unroll
    for (int c = 0; c < 4; ++c) {
        float z = acc[c];
        z = z > 0.f ? z : 0.01f * z;
        float sg = 1.f / (1.f + __expf(-z));
        h[c] = 1.5707963267948966f * sg;
    }

    float sr[16], si[16];
    #pragma unroll
    for (int i = 0; i < 16; ++i) { sr[i] = 0.f; si[i] = 0.f; }
    sr[0] = 1.f;

    float ce, se;
    __sincosf(h[0], &se, &ce); ry_b<8>(sr, si, ce, se);
    __sincosf(h[1], &se, &ce); ry_b<4>(sr, si, ce, se);
    __sincosf(h[2], &se, &ce); ry_b<2>(sr, si, ce, se);
    __sincosf(h[3], &se, &ce); ry_b<1>(sr, si, ce, se);

    float cs0[7], sn0[7], cs1[7], sn1[7];
    #pragma unroll
    for (int k = 0; k < 7; ++k) {
        __sincosf(qp[k] * 0.5f, &sn0[k], &cs0[k]);
        __sincosf(qp[7 + k] * 0.5f, &sn1[k], &cs1[k]);
    }
    ansatz<0, 1>(sr, si, cs0, sn0);
    ansatz<1, 2>(sr, si, cs0, sn0);
    ansatz<2, 3>(sr, si, cs0, sn0);
    ansatz<3, 0>(sr, si, cs0, sn0);
    ansatz<0, 1>(sr, si, cs1, sn1);
    ansatz<1, 2>(sr, si, cs1, sn1);
    ansatz<2, 3>(sr, si, cs1, sn1);
    ansatz<3, 0>(sr, si, cs1, sn1);

    float p[16];
    #pragma unroll
    for (int i = 0; i < 16; ++i) p[i] = sr[i] * sr[i] + si[i] * si[i];

    float* qo = q + n * 196 + pp * 4;
    #pragma unroll
    for (int w = 0; w < 4; ++w) {
        int B = 8 >> w;
        float e = 0.f;
        #pragma unroll
        for (int i = 0; i < 16; ++i) e += (i & B) ? -p[i] : p[i];
        qo[w] = e;
    }
}

// ============================ fused MLP ============================
__global__ __launch_bounds__(64) void fc_kernel(
    const float* __restrict__ q,
    const float* __restrict__ fc1t, const float* __restrict__ fb1,
    const float* __restrict__ fc2t, const float* __restrict__ fb2,
    const float* __restrict__ fc3t, const float* __restrict__ fb3,
    const float* __restrict__ fc4t, const float* __restrict__ fb4,
    float* __restrict__ out)
{
    __shared__ float qr[196], h1[64], h2[128], h3[64];
    int n = blockIdx.x, t = threadIdx.x;
    for (int i = t; i < 196; i += 64) qr[i] = q[n * 196 + i];
    __syncthreads();
    float a = fb1[t];
    for (int k = 0; k < 196; ++k) a = fmaf(fc1t[k * 64 + t], qr[k], a);
    h1[t] = fmaxf(a, 0.f);
    __syncthreads();
    float a0 = fb2[t], a1 = fb2[t + 64];
    for (int k = 0; k < 64; ++k) {
        float v = h1[k];
        a0 = fmaf(fc2t[k * 128 + t], v, a0);
        a1 = fmaf(fc2t[k * 128 + t + 64], v, a1);
    }
    h2[t] = a0; h2[t + 64] = a1;
    __syncthreads();
    a = fb3[t];
    for (int k = 0; k < 128; ++k) a = fmaf(fc3t[k * 64 + t], h2[k], a);
    h3[t] = fmaxf(a, 0.f);
    __syncthreads();
    if (t < 10) {
        a = fb4[t];
        for (int k = 0; k < 64; ++k) a = fmaf(fc4t[k * 10 + t], h3[k], a);
        out[n * 10 + t] = a;
    }
}

// ============================ launch ============================
extern "C" void kernel_launch(void* const* d_in, const int* in_sizes, int n_in,
                              void* d_out, int out_size, void* d_ws, size_t ws_size,
                              hipStream_t stream) {
    const float* x      = (const float*)d_in[0];
    const float* c1w    = (const float*)d_in[1];
    const float* c1b    = (const float*)d_in[2];
    const float* c2w    = (const float*)d_in[3];
    const float* c2b    = (const float*)d_in[4];
    const float* c3w    = (const float*)d_in[5];
    const float* c3b    = (const float*)d_in[6];
    const float* qp     = (const float*)d_in[7];
    const float* fc1w   = (const float*)d_in[8];
    const float* fc1b   = (const float*)d_in[9];
    const float* fc2w   = (const float*)d_in[10];
    const float* fc2b   = (const float*)d_in[11];
    const float* fc3w   = (const float*)d_in[12];
    const float* fc3b   = (const float*)d_in[13];
    const float* fc4w   = (const float*)d_in[14];
    const float* fc4b   = (const float*)d_in[15];
    float* out = (float*)d_out;

    float* ws = (float*)d_ws;
    unsigned short* w2b = (unsigned short*)ws;            // 9216 bf16 (4608 float slots)
    float* fc1t = ws + 4608;                              // 12544
    float* fc2t = fc1t + 12544;                           // 8192
    float* fc3t = fc2t + 8192;                            // 8192
    float* fc4t = fc3t + 8192;                            // 640
    unsigned short* out1 = (unsigned short*)(fc4t + 640); // 2048*12544 bf16 (NHWC)
    float* out2 = (float*)(out1 + (size_t)2048 * 12544);  // 2048*784 f32
    float* qbuf = out2 + (size_t)2048 * 784;              // 2048*196 f32

    prep_kernel<<<40, 256, 0, stream>>>(c2w, fc1w, fc2w, fc3w, fc4w,
                                        w2b, fc1t, fc2t, fc3t, fc4t);
    conv1_kernel<<<2048, 256, 0, stream>>>(x, c1w, c1b, out1);
    conv2_kernel<<<2048, 256, 0, stream>>>(out1, w2b, c2b, out2);
    qconv_kernel<<<392, 256, 0, stream>>>(out2, c3w, c3b, qp, qbuf);
    fc_kernel<<<2048, 64, 0, stream>>>(qbuf, fc1t, fc1b, fc2t, fc2b,
                                       fc3t, fc3b, fc4t, fc4b, out);
}